// Round 13
// baseline (113.040 us; speedup 1.0000x reference)
//
#include <hip/hip_runtime.h>
#include <hip/hip_bf16.h>

// NT-Xent, BATCH=4096, N=8192, D=512, TEMP=0.1 — bf16 MFMA.
// Round 13: faithful m201-style 8-phase template. 256x256 tile, BK=64,
// 8 waves (2M x 4N, per-wave 128x64), 128 KB LDS (2 buf x (A,B) x 32 KB),
// 1 half-tile staged per phase (2 GLDS), vmcnt(2) at phases 4/8 only,
// per phase: {ds_read subtile; stage; BAR; lgkmcnt(0); setprio MFMA x16; BAR}.
// loss = mean_i [ logsumexp_{j!=i} sim[i,j] - sim[i,partner(i)] ]
// acc  = mean_i [ sim[i,partner(i)] >= max_{j!=i,partner} sim[i,j] ]
// sim = (msg_n . img_n^T)/TEMP, 10x folded into msg side before bf16 cast.

#define NROWS 8192
#define BATCHD 4096
#define DIM 512
#define BM 256
#define BN 256
#define BK 64
#define SHIFT 10.0f

typedef short bf16x8 __attribute__((ext_vector_type(8)));
typedef float f32x4 __attribute__((ext_vector_type(4)));

#define GLDS(g, l)                                                             \
    __builtin_amdgcn_global_load_lds(                                          \
        (const __attribute__((address_space(1))) void*)(g),                    \
        (__attribute__((address_space(3))) void*)(l), 16, 0, 0)

__device__ __forceinline__ unsigned f2u_ord(float f) {
    unsigned u = __float_as_uint(f);
    return (u & 0x80000000u) ? ~u : (u | 0x80000000u);
}
__device__ __forceinline__ float u2f_ord(unsigned e) {
    return (e & 0x80000000u) ? __uint_as_float(e & 0x7fffffffu) : __uint_as_float(~e);
}
__device__ __forceinline__ short f2bf(float f) {  // RNE f32 -> bf16 bits
    unsigned u = __float_as_uint(f);
    return (short)((u + 0x7fffu + ((u >> 16) & 1u)) >> 16);
}

// blocks 0..NROWS-1: msg (x10); NROWS..2*NROWS-1: img (x1).
// First 128 blocks also zero rowsum/rowmax/accum.
__global__ __launch_bounds__(64) void normalize_bf16_both(const float* __restrict__ msg,
                                                          const float* __restrict__ img,
                                                          short* __restrict__ mnb,
                                                          short* __restrict__ imb,
                                                          float* __restrict__ rowsum,
                                                          unsigned* __restrict__ rowmax,
                                                          float* __restrict__ accum) {
    if (blockIdx.x < 128) {
        const int i = blockIdx.x * 64 + threadIdx.x;
        rowsum[i] = 0.f;
        rowmax[i] = 0u;  // encodes "most negative"
        if (i < 2) accum[i] = 0.f;
    }
    int row = blockIdx.x;
    const float* in;
    short* out;
    float scale;
    if (row < NROWS) { in = msg; out = mnb; scale = 10.0f; }
    else { row -= NROWS; in = img; out = imb; scale = 1.0f; }
    const int lane = threadIdx.x;
    const float* src = in + (size_t)row * DIM + lane * 8;
    float4 v0 = *(const float4*)(src);
    float4 v1 = *(const float4*)(src + 4);
    float ss = v0.x*v0.x + v0.y*v0.y + v0.z*v0.z + v0.w*v0.w
             + v1.x*v1.x + v1.y*v1.y + v1.z*v1.z + v1.w*v1.w;
    #pragma unroll
    for (int off = 1; off < 64; off <<= 1) ss += __shfl_xor(ss, off);
    const float inv = scale / fmaxf(sqrtf(ss), 1e-8f);
    float vv[8] = {v0.x, v0.y, v0.z, v0.w, v1.x, v1.y, v1.z, v1.w};
    bf16x8 o;
    #pragma unroll
    for (int j = 0; j < 8; ++j) o[j] = f2bf(vv[j] * inv);
    *(bf16x8*)(out + (size_t)row * DIM + lane * 8) = o;
}

// A = msg_n*10 (bf16), B = img_n (bf16); row-major [8192][512].
// LDS per buffer per matrix: [256 rows][8 chunks of 16B]; chunk-slot p of
// row r holds logical chunk p ^ (r&7); linear GLDS dest, pre-swizzled source.
// Quadrant order per K-tile: (mh,nh) = (0,0),(0,1),(1,1),(1,0) — A frags
// reused across 2 consecutive phases.
__global__ __launch_bounds__(512, 2) void simloss_mfma(const short* __restrict__ A,
                                                       const short* __restrict__ B,
                                                       float* __restrict__ rowsum,
                                                       unsigned* __restrict__ rowmax,
                                                       float* __restrict__ rowpos) {
    __shared__ short As[2][BM * BK];  // 2 x 32 KB
    __shared__ short Bs[2][BN * BK];  // 2 x 32 KB  -> 128 KB total

    const int tid = threadIdx.x;
    const int lane = tid & 63;
    const int g = lane >> 4;     // k-group 0..3 (8 bf16 each within K=32)
    const int r16 = lane & 15;
    const int swz = r16 & 7;
    const int wid = tid >> 6;
    const int wr = wid >> 2;     // 0..1  (M waves, 128 rows each)
    const int wc = wid & 3;      // 0..3  (N waves, 64 cols each)

    // XCD stripes, bx-major traversal (by fastest): 1024 blocks = 32 by x 32 bx.
    const int bid = blockIdx.x;
    const int xcd = bid & 7;
    const int l = bid >> 3;          // 0..127
    const int by = xcd * 4 + (l & 3);
    const int bx = l >> 2;           // 0..31
    const int rowBase = by * BM;
    const int colBase = bx * BN;

    // staging: half-tile hh = 128 rows = 1024 slots of 16B; thread covers
    // slots {tid, tid+512}: row_local = tid>>3 (+64), chunk = (tid&7)^(row&7).
    const int rS = tid >> 3;                 // 0..63
    const int cS = (tid & 7) ^ (rS & 7);
    const short* pA = A + (size_t)(rowBase + rS) * DIM + cS * 8;
    const short* pB = B + (size_t)(colBase + rS) * DIM + cS * 8;

#define STAGE_A(b, hh, koff)                                                      \
    do {                                                                          \
        GLDS(pA + (size_t)(hh) * 128 * DIM + (koff), &As[b][((hh)*1024 + tid) * 8]);       \
        GLDS(pA + (size_t)((hh) * 128 + 64) * DIM + (koff), &As[b][((hh)*1024 + 512 + tid) * 8]); \
    } while (0)
#define STAGE_B(b, hh, koff)                                                      \
    do {                                                                          \
        GLDS(pB + (size_t)(hh) * 128 * DIM + (koff), &Bs[b][((hh)*1024 + tid) * 8]);       \
        GLDS(pB + (size_t)((hh) * 128 + 64) * DIM + (koff), &Bs[b][((hh)*1024 + 512 + tid) * 8]); \
    } while (0)

    // fragment reads: row*64 + ((g^swz))*8 shorts; kk=1 chunk = kk0 ^ 4 -> ^32.
    const int gk = (g ^ swz) * 8;
    const int aRow0 = wr * 128 + r16;
    const int bRow0 = wc * 64 + r16;

    f32x4 acc[8][4] = {};
    bf16x8 af[4][2], bf[2][2];

#define LDA(b, mh)                                                             \
    do {                                                                       \
        _Pragma("unroll") for (int m = 0; m < 4; ++m) {                        \
            const int ad = (aRow0 + (mh) * 64 + m * 16) * 64 + gk;             \
            af[m][0] = *(const bf16x8*)&As[b][ad];                             \
            af[m][1] = *(const bf16x8*)&As[b][ad ^ 32];                        \
        }                                                                      \
    } while (0)
#define LDB(b, nh)                                                             \
    do {                                                                       \
        _Pragma("unroll") for (int n = 0; n < 2; ++n) {                        \
            const int bd = (bRow0 + (nh) * 32 + n * 16) * 64 + gk;             \
            bf[n][0] = *(const bf16x8*)&Bs[b][bd];                             \
            bf[n][1] = *(const bf16x8*)&Bs[b][bd ^ 32];                        \
        }                                                                      \
    } while (0)
#define MFMA16(mh, nh)                                                         \
    do {                                                                       \
        __builtin_amdgcn_s_setprio(1);                                         \
        _Pragma("unroll") for (int kk = 0; kk < 2; ++kk)                       \
            _Pragma("unroll") for (int m = 0; m < 4; ++m)                      \
                _Pragma("unroll") for (int n = 0; n < 2; ++n)                  \
                    acc[(mh)*4 + m][(nh)*2 + n] =                              \
                        __builtin_amdgcn_mfma_f32_16x16x32_bf16(               \
                            af[m][kk], bf[n][kk], acc[(mh)*4 + m][(nh)*2 + n], \
                            0, 0, 0);                                          \
        __builtin_amdgcn_s_setprio(0);                                         \
    } while (0)
#define VMCNT(n) asm volatile("s_waitcnt vmcnt(" #n ")" ::: "memory")
#define LGKM0 asm volatile("s_waitcnt lgkmcnt(0)" ::: "memory")
#define BAR() __builtin_amdgcn_s_barrier()

    // prologue: tile 0 full into buf0, tile 1 A-half0 into buf1.
    STAGE_A(0, 0, 0); STAGE_A(0, 1, 0);
    STAGE_B(0, 0, 0); STAGE_B(0, 1, 0);
    STAGE_A(1, 0, BK);
    VMCNT(2);  // tile 0's 8 GLDS landed; tile1-A0 may fly
    BAR();

    for (int j = 0; j < 4; ++j) {
        const int k1 = (2 * j + 1) * BK;   // tile 2j+1 (buf1, computed ph5-8)
        const int k2 = (2 * j + 2) * BK;   // tile 2j+2 (buf0, next iter ph1-4)
        const int k3 = (2 * j + 3) * BK;   // tile 2j+3 (buf1, next iter ph5-8)
        const bool st = (j < 3);
        // ph1: buf0 quad (0,0); stage A1 of tile 2j+1 -> buf1
        LDA(0, 0); LDB(0, 0);
        STAGE_A(1, 1, k1);
        BAR(); LGKM0; MFMA16(0, 0); BAR();
        // ph2: buf0 quad (0,1); stage B0 tile 2j+1
        LDB(0, 1);
        STAGE_B(1, 0, k1);
        BAR(); LGKM0; MFMA16(0, 1); BAR();
        // ph3: buf0 quad (1,1); stage B1 tile 2j+1
        LDA(0, 1);
        STAGE_B(1, 1, k1);
        BAR(); LGKM0; MFMA16(1, 1); BAR();
        // ph4: buf0 quad (1,0); stage A0 tile 2j+2 -> buf0 (A dead after ph3)
        LDB(0, 0);
        if (st) { STAGE_A(0, 0, k2); VMCNT(2); } else VMCNT(0);
        BAR(); LGKM0; MFMA16(1, 0); BAR();
        // ph5: buf1 quad (0,0); stage A1 tile 2j+2
        LDA(1, 0); LDB(1, 0);
        if (st) STAGE_A(0, 1, k2);
        BAR(); LGKM0; MFMA16(0, 0); BAR();
        // ph6: buf1 quad (0,1); stage B0 tile 2j+2 (buf0 B dead after ph4)
        LDB(1, 1);
        if (st) STAGE_B(0, 0, k2);
        BAR(); LGKM0; MFMA16(0, 1); BAR();
        // ph7: buf1 quad (1,1); stage B1 tile 2j+2
        LDA(1, 1);
        if (st) STAGE_B(0, 1, k2);
        BAR(); LGKM0; MFMA16(1, 1); BAR();
        // ph8: buf1 quad (1,0); stage A0 tile 2j+3 -> buf1 (A dead after ph7)
        LDB(1, 0);
        if (st) { STAGE_A(1, 0, k3); VMCNT(2); }
        BAR(); LGKM0; MFMA16(1, 0); BAR();
    }

    // ---- fused epilogue ----
    // C/D layout: col = lane&15 (r16), row = g*4 + reg  [m89 verified]
    __syncthreads();
    float* ssum = (float*)&As[0][0];   // 256*4 floats
    float* smx = ssum + 1024;          // 256*4 floats
    const int baseRowW = rowBase + wr * 128 + g * 4;
    const int baseColW = colBase + wc * 64 + r16;
    #pragma unroll
    for (int m = 0; m < 8; ++m) {
        #pragma unroll
        for (int reg = 0; reg < 4; ++reg) {
            const int i = baseRowW + m * 16 + reg;
            const int partner = i ^ BATCHD;
            float sum = 0.f, mx = -1e30f;
            #pragma unroll
            for (int n = 0; n < 4; ++n) {
                const int j = baseColW + n * 16;
                const float s = acc[m][n][reg];
                const bool isDiag = (j == i);
                const bool isPos = (j == partner);
                float e = __expf(s - SHIFT);
                if (isDiag) e = 0.f;
                sum += e;
                if (!isDiag && !isPos) mx = fmaxf(mx, s);
                if (isPos) rowpos[i] = s;  // exactly one writer grid-wide
            }
            #pragma unroll
            for (int off = 1; off < 16; off <<= 1) {
                sum += __shfl_xor(sum, off);
                mx = fmaxf(mx, __shfl_xor(mx, off));
            }
            if (r16 == 0) {
                const int rloc = wr * 128 + m * 16 + g * 4 + reg;
                ssum[rloc * 4 + wc] = sum;
                smx[rloc * 4 + wc] = mx;
            }
        }
    }
    __syncthreads();
    // combine the 4 column-waves' partials: one atomic pair per row per block
    if (tid < 256) {
        const float s = ssum[tid * 4 + 0] + ssum[tid * 4 + 1] +
                        ssum[tid * 4 + 2] + ssum[tid * 4 + 3];
        const float mx = fmaxf(fmaxf(smx[tid * 4 + 0], smx[tid * 4 + 1]),
                               fmaxf(smx[tid * 4 + 2], smx[tid * 4 + 3]));
        const int i = rowBase + tid;
        atomicAdd(&rowsum[i], s);
        atomicMax(&rowmax[i], f2u_ord(mx));
    }
#undef STAGE_A
#undef STAGE_B
#undef LDA
#undef LDB
#undef MFMA16
#undef VMCNT
#undef LGKM0
#undef BAR
}

// 32 blocks x 256 threads: one row per thread, block-reduce, atomic combine.
__global__ __launch_bounds__(256) void finalize_partial(const float* __restrict__ rowsum,
                                                        const unsigned* __restrict__ rowmax,
                                                        const float* __restrict__ rowpos,
                                                        float* __restrict__ accum) {
    const int tid = threadIdx.x;
    const int i = blockIdx.x * 256 + tid;
    const float lse = SHIFT + logf(rowsum[i]);
    const float pos = rowpos[i];
    float lossAcc = lse - pos;
    float hitAcc = (pos >= u2f_ord(rowmax[i])) ? 1.f : 0.f;
    __shared__ float sl[256], sa[256];
    sl[tid] = lossAcc; sa[tid] = hitAcc;
    __syncthreads();
    for (int s = 128; s > 0; s >>= 1) {
        if (tid < s) { sl[tid] += sl[tid + s]; sa[tid] += sa[tid + s]; }
        __syncthreads();
    }
    if (tid == 0) {
        atomicAdd(&accum[0], sl[0]);
        atomicAdd(&accum[1], sa[0]);
    }
}

__global__ void finalize_write(const float* __restrict__ accum, float* __restrict__ out) {
    if (threadIdx.x == 0) {
        out[0] = accum[0] / (float)NROWS;
        out[1] = accum[1] / (float)NROWS;
    }
}

extern "C" void kernel_launch(void* const* d_in, const int* in_sizes, int n_in,
                              void* d_out, int out_size, void* d_ws, size_t ws_size,
                              hipStream_t stream) {
    const float* msg = (const float*)d_in[0];
    const float* img = (const float*)d_in[1];
    float* out = (float*)d_out;

    char* ws = (char*)d_ws;
    const size_t matBytes = (size_t)NROWS * DIM * sizeof(short);  // 8 MB
    short* mnb = (short*)ws;
    short* imb = (short*)(ws + matBytes);
    float* rowsum = (float*)(ws + 2 * matBytes);
    unsigned* rowmax = (unsigned*)(ws + 2 * matBytes + NROWS * sizeof(float));
    float* rowpos = (float*)(ws + 2 * matBytes + 2 * NROWS * sizeof(float));
    float* accum = (float*)(ws + 2 * matBytes + 3 * NROWS * sizeof(float));

    normalize_bf16_both<<<2 * NROWS, 64, 0, stream>>>(msg, img, mnb, imb,
                                                      rowsum, rowmax, accum);

    simloss_mfma<<<(NROWS / BM) * (NROWS / BN), 512, 0, stream>>>(mnb, imb, rowsum,
                                                                  rowmax, rowpos);

    finalize_partial<<<NROWS / 256, 256, 0, stream>>>(rowsum, rowmax, rowpos, accum);
    finalize_write<<<1, 64, 0, stream>>>(accum, out);
}